// Round 9
// baseline (139.983 us; speedup 1.0000x reference)
//
#include <hip/hip_runtime.h>
#include <hip/hip_bf16.h>

#define B_  2
#define T_  2048
#define D_  1024
#define H_  16
#define DH_ 64
#define M_  (B_ * T_)   // 4096 rows

typedef short s16x8 __attribute__((ext_vector_type(8)));
typedef float f32x4 __attribute__((ext_vector_type(4)));

__device__ inline float bfu(unsigned short u) {
    union { unsigned int i; float f; } c; c.i = ((unsigned int)u) << 16; return c.f;
}
__device__ inline unsigned short f2bf(float f) {   // round-to-nearest-even
    union { float f; unsigned int i; } c; c.f = f;
    unsigned int r = c.i + 0x7fffu + ((c.i >> 16) & 1u);
    return (unsigned short)(r >> 16);
}
// C-store: fp32 path is the final output (never re-read) -> non-temporal
// (R8 WIN, -6.8us: streaming fp32 writes were evicting the L2-resident
// qb/Wob working set). bf16 path (q/k) is re-read by swa -> cacheable.
__device__ inline void stv(float* p, float v) { __builtin_nontemporal_store(v, p); }
__device__ inline void stv(unsigned short* p, float v) { *p = f2bf(v); }

// async global->LDS, 16B per lane; lds base must be wave-uniform (HW adds lane*16)
__device__ inline void gload_lds16(const unsigned short* g, unsigned short* l) {
    __builtin_amdgcn_global_load_lds(
        (const __attribute__((address_space(1))) void*)g,
        (__attribute__((address_space(3))) void*)l, 16, 0, 0);
}

// ---------------------------------------------------------------------------
// Device-scope grid barrier for the persistent fused kernel. Counters are
// memset(0) in-stream before launch; ticket form also tolerates any initial
// value that is a multiple of nblk. Safe only when all nblk blocks are
// co-resident — guaranteed by the host-side occupancy gate (fallback path
// otherwise). threadfence = device-scope release/acquire across XCD L2s.
// ---------------------------------------------------------------------------
__device__ inline void gridbar(int* c, int nblk) {
    __syncthreads();
    __threadfence();
    if (threadIdx.x == 0) {
        int t = atomicAdd(c, 1) + 1;
        int target = ((t + nblk - 1) / nblk) * nblk;
        while (__hip_atomic_load(c, __ATOMIC_RELAXED, __HIP_MEMORY_SCOPE_AGENT) < target)
            __builtin_amdgcn_s_sleep(16);
    }
    __syncthreads();
    __threadfence();
}

// ---------------------------------------------------------------------------
// fp32 -> bf16 conversion work (x and the 4 weights into one contiguous blob).
// ---------------------------------------------------------------------------
__device__ __forceinline__ void conv_work(const float* __restrict__ x,
                                          const float* __restrict__ Wq,
                                          const float* __restrict__ Wk,
                                          const float* __restrict__ Wv,
                                          const float* __restrict__ Wo,
                                          unsigned short* __restrict__ dst,
                                          int nblocks) {
    for (int g = blockIdx.x * 256 + threadIdx.x; g < (1 << 21); g += nblocks * 256) {
        const float* s; size_t o;
        if (g < (1 << 20)) { s = x; o = (size_t)g; }
        else {
            int gg = g - (1 << 20);
            int w = gg >> 18;
            o = (size_t)(gg & ((1 << 18) - 1));
            s = (w == 0) ? Wq : (w == 1) ? Wk : (w == 2) ? Wv : Wo;
        }
        float4 v = ((const float4*)s)[o];
        ushort4 u;
        u.x = f2bf(v.x); u.y = f2bf(v.y); u.z = f2bf(v.z); u.w = f2bf(v.w);
        ((ushort4*)dst)[g] = u;
    }
}

__global__ __launch_bounds__(256) void conv_bf16(const float* __restrict__ x,
                                                 const float* __restrict__ Wq,
                                                 const float* __restrict__ Wk,
                                                 const float* __restrict__ Wv,
                                                 const float* __restrict__ Wo,
                                                 unsigned short* __restrict__ dst) {
    conv_work(x, Wq, Wk, Wv, Wo, dst, 2048);
}

// ---------------------------------------------------------------------------
// m97-style MFMA NT GEMM tile body, BK = 32*NH stacked half-tiles. BM x BN,
// 256 thr (2x2 waves of (BM/2)x(BN/2)), 16x16x32 MFMA, fp32 acc.
// 16x16 fragment ds_reads sweep a full 1KB window/wave = conflict-free (R7:
// 32x32 frags broke this, 9.4M bank conflicts; reverted).
// R1: 256^2 8-phase loses at these grids. r11: BN=64 regressed (16 MFMA/drain).
// R4 (WIN): XCD by-chunk remap — A-chunk L2-resident; out-proj WS fits L2.
// Output: bn<1024 -> C0, bn<2048 -> C1, bn>=2048 (vtr!=null) -> V transposed
// to vtr[(b*16+h)*64+d][t] (packed ushort4: r = 4 consecutive t).
// ---------------------------------------------------------------------------
template <int BM, int BN, int NH, typename Tout>
__device__ __forceinline__ void gemm_tile(unsigned short* As, unsigned short* Bs,
                                          const unsigned short* __restrict__ A,
                                          const unsigned short* __restrict__ Bw,
                                          Tout* __restrict__ C0, Tout* __restrict__ C1,
                                          unsigned short* __restrict__ vtr, int K,
                                          int hw, int gx, int nwg) {
    constexpr int MI = BM / 32;                   // m-frags per wave
    constexpr int NI = BN / 32;                   // n-frags per wave
    const int tid  = threadIdx.x;
    const int lane = tid & 63;
    const int wave = tid >> 6;
    const int wr = wave >> 1, wc = wave & 1;

    // XCD by-chunk remap (nwg % 8 == 0 -> bijective)
    const int l   = (hw & 7) * (nwg >> 3) + (hw >> 3);
    const int bxl = l % gx, byl = l / gx;
    const int bm = byl * BM, bn = bxl * BN;

    const int fr = lane & 15, kg = lane >> 4;
    const int lrow = lane >> 2;          // staging row within 16-row window
    const int lcol = (lane & 3) * 8;     // staging 16B chunk (ushort offset)

    f32x4 acc[MI][NI];
    #pragma unroll
    for (int mi = 0; mi < MI; ++mi)
        #pragma unroll
        for (int ni = 0; ni < NI; ++ni)
            #pragma unroll
            for (int r = 0; r < 4; ++r) acc[mi][ni][r] = 0.f;

    const unsigned short* ga = A  + (size_t)(bm + wave * 16 + lrow) * K + lcol;
    const unsigned short* gb = Bw + (size_t)(bn + wave * 16 + lrow) * K + lcol;
    unsigned short* la = &As[(wave * 16) * 32];   // wave-uniform
    unsigned short* lb = &Bs[(wave * 16) * 32];

    for (int k0 = 0; k0 < K; k0 += 32 * NH) {
        __syncthreads();                          // prev-iter LDS reads done
        #pragma unroll
        for (int hf = 0; hf < NH; ++hf) {
            #pragma unroll
            for (int s = 0; s < BM / 64; ++s)
                gload_lds16(ga + k0 + hf * 32 + (size_t)(s * 64) * K,
                            la + hf * BM * 32 + s * 64 * 32);
            #pragma unroll
            for (int s = 0; s < BN / 64; ++s)
                gload_lds16(gb + k0 + hf * 32 + (size_t)(s * 64) * K,
                            lb + hf * BN * 32 + s * 64 * 32);
        }
        __syncthreads();                          // vmcnt drained: tile visible
        #pragma unroll
        for (int hf = 0; hf < NH; ++hf) {
            s16x8 af[MI], bfv[NI];
            #pragma unroll
            for (int mi = 0; mi < MI; ++mi)
                af[mi] = *(const s16x8*)&As[hf * BM * 32 + (wr * (BM / 2) + mi * 16 + fr) * 32 + kg * 8];
            #pragma unroll
            for (int ni = 0; ni < NI; ++ni)
                bfv[ni] = *(const s16x8*)&Bs[hf * BN * 32 + (wc * (BN / 2) + ni * 16 + fr) * 32 + kg * 8];
            #pragma unroll
            for (int mi = 0; mi < MI; ++mi)
                #pragma unroll
                for (int ni = 0; ni < NI; ++ni)
                    acc[mi][ni] = __builtin_amdgcn_mfma_f32_16x16x32_bf16(af[mi], bfv[ni], acc[mi][ni], 0, 0, 0);
        }
    }

    if (vtr && bn >= 2048) {
        // V n-tile: write transposed, packed over r (4 consecutive t)
        #pragma unroll
        for (int mi = 0; mi < MI; ++mi)
            #pragma unroll
            for (int ni = 0; ni < NI; ++ni) {
                const int nl = (bn - 2048) + wc * (BN / 2) + ni * 16 + fr;
                const int h = nl >> 6, d = nl & 63;
                const int m0 = bm + wr * (BM / 2) + mi * 16 + kg * 4;
                const int b = m0 >> 11, t0 = m0 & (T_ - 1);
                ushort4 u;
                u.x = f2bf(acc[mi][ni][0]); u.y = f2bf(acc[mi][ni][1]);
                u.z = f2bf(acc[mi][ni][2]); u.w = f2bf(acc[mi][ni][3]);
                *(ushort4*)(vtr + ((size_t)(b * H_ + h) * 64 + d) * T_ + t0) = u;
            }
        return;
    }
    Tout* C = (bn < 1024) ? C0 : C1;
    const int nb = bn & 1023;
    #pragma unroll
    for (int mi = 0; mi < MI; ++mi)
        #pragma unroll
        for (int ni = 0; ni < NI; ++ni)
            #pragma unroll
            for (int r = 0; r < 4; ++r) {
                int m = bm + wr * (BM / 2) + mi * 16 + kg * 4 + r;
                int n = nb + wc * (BN / 2) + ni * 16 + fr;
                stv(&C[(size_t)m * 1024 + n], acc[mi][ni][r]);
            }
}

template <int BM, int BN, int NH, typename Tout>
__global__ __launch_bounds__(256, 4) void gemm_m97(const unsigned short* __restrict__ A,
                                                   const unsigned short* __restrict__ Bw,
                                                   Tout* __restrict__ C0,
                                                   Tout* __restrict__ C1,
                                                   unsigned short* __restrict__ vtr,
                                                   int K) {
    __shared__ __align__(16) unsigned short As[NH * BM * 32];
    __shared__ __align__(16) unsigned short Bs[NH * BN * 32];
    gemm_tile<BM, BN, NH, Tout>(As, Bs, A, Bw, C0, C1, vtr, K,
                                blockIdx.x + gridDim.x * blockIdx.y,
                                gridDim.x, gridDim.x * gridDim.y);
}

// ---------------------------------------------------------------------------
// MFMA sliding-window attention tile (validated r11 + R4/R5). 64 queries of
// one (b,h). K window [klo2,+192) and V^T window [klo2,+208) staged via
// global_load_lds with XOR chunk swizzle; P reuses dead Ks after QK^T.
// R2 (null): 128q/8-wave. R6 (regression): de-staging V (staged V = prefetch
// hidden behind the K barrier). R4 (WIN): XCD head-chunk remap (4 heads =
// 2MB K+V per XCD L2). R5 (WIN): s_setprio around MFMA clusters.
// ---------------------------------------------------------------------------
__device__ __forceinline__ void swa_tile(unsigned short* Ks, unsigned short* Vs,
                                         const unsigned short* qb,
                                         const unsigned short* __restrict__ kb,
                                         const unsigned short* __restrict__ vt,
                                         unsigned short* ob, int traw) {
    __syncthreads();                               // protect LDS reuse
    const int wave = threadIdx.x >> 6;
    const int lane = threadIdx.x & 63;
    const int blk = (traw & 7) * 128 + (traw >> 3);  // XCD head-chunk
    const int i0b = (blk & 31) * 64;               // block's first query
    const int bh  = blk >> 5;
    const int h = bh & (H_ - 1), b = bh >> 4;
    const int g = lane >> 4, l15 = lane & 15;

    const size_t rowbase = (size_t)b * T_ * D_ + (size_t)h * DH_;
    const int klo2 = (i0b > 128) ? (i0b - 128) : 0;   // <= 1856

    // ---- stage K rows [klo2, +192), XOR-swizzled chunks ----
    {
        const int lr = lane >> 3;                  // 0..7
        const int gc = (lane & 7) ^ lr;            // global chunk to fetch
        const unsigned short* kg0 = kb + rowbase + (size_t)(klo2 + lr) * D_ + gc * 8;
        #pragma unroll
        for (int s = 0; s < 6; ++s) {
            const int i = wave * 6 + s;            // 24 instrs, 8 rows each
            gload_lds16(kg0 + (size_t)(i * 8) * D_, &Ks[i * 8 * 64]);
        }
    }
    // ---- stage V^T rows d=0..63, cols [klo2, +208), 26 chunks/row ----
    {
        const unsigned short* vtb = vt + (size_t)bh * 64 * T_ + klo2;
        #pragma unroll
        for (int s = 0; s < 7; ++s) {
            const int i = s * 4 + wave;            // wave-uniform
            if (i < 26) {
                const int cc = i * 64 + lane;      // flat chunk 0..1663
                const int d  = cc / 26;
                const int sl = cc - d * 26;        // LDS slot 0..25
                const int c  = (sl < 24) ? (sl ^ (d & 7)) : sl;  // global chunk
                gload_lds16(vtb + (size_t)d * T_ + c * 8, &Vs[i * 512]);
            }
        }
    }

    const int i0  = i0b + wave * 16;
    const int klo = (i0 > 128) ? (i0 - 128) : 0;
    const int koff = klo - klo2;                   // 0,16,32,48

    // Q fragments from global (issued before barrier: overlap staging drain)
    const unsigned short* qrow = qb + rowbase + (size_t)(i0 + l15) * D_ + g * 8;
    const s16x8 aq0 = *(const s16x8*)(qrow);
    const s16x8 aq1 = *(const s16x8*)(qrow + 32);

    __syncthreads();                               // K+V windows visible

    // ---- S = Q K^T over 9 key tiles (B-frags from swizzled Ks) ----
    f32x4 sacc[9];
    #pragma unroll
    for (int t = 0; t < 9; ++t)
        #pragma unroll
        for (int r = 0; r < 4; ++r) sacc[t][r] = 0.f;

    #pragma unroll
    for (int t = 0; t < 9; ++t) {
        const int row = koff + t * 16 + l15;       // <= 191
        const int r7 = row & 7;
        s16x8 b0 = *(const s16x8*)&Ks[row * 64 + ((g     ^ r7) * 8)];
        s16x8 b1 = *(const s16x8*)&Ks[row * 64 + (((g+4) ^ r7) * 8)];
        __builtin_amdgcn_s_setprio(1);
        sacc[t] = __builtin_amdgcn_mfma_f32_16x16x32_bf16(aq0, b0, sacc[t], 0, 0, 0);
        sacc[t] = __builtin_amdgcn_mfma_f32_16x16x32_bf16(aq1, b1, sacc[t], 0, 0, 0);
        __builtin_amdgcn_s_setprio(0);
    }

    __syncthreads();                               // Ks dead -> P may reuse it
    unsigned short* Pw = &Ks[wave * (16 * 168)];   // 4 x 5376 B, 16B-aligned
    {   // zero-pad P cols 144..159 (read by last PV k-tile)
        int row = lane >> 2, col = 144 + (lane & 3) * 4;
        *(uint2*)&Pw[row * 168 + col] = make_uint2(0u, 0u);
    }

    // ---- mask + scale + softmax (C/D layout: row g*4+r, col l15) ----
    float mrow[4] = {-1e30f, -1e30f, -1e30f, -1e30f};
    #pragma unroll
    for (int t = 0; t < 9; ++t)
        #pragma unroll
        for (int r = 0; r < 4; ++r) {
            const int j  = klo + t * 16 + l15;
            const int iq = i0 + g * 4 + r;
            const bool valid = (j <= iq) && (j + 128 >= iq);
            const float s = valid ? sacc[t][r] * 0.125f : -1e30f;
            sacc[t][r] = s;
            mrow[r] = fmaxf(mrow[r], s);
        }
    #pragma unroll
    for (int r = 0; r < 4; ++r)
        #pragma unroll
        for (int off = 1; off < 16; off <<= 1)
            mrow[r] = fmaxf(mrow[r], __shfl_xor(mrow[r], off));

    float lrow[4] = {0.f, 0.f, 0.f, 0.f};
    #pragma unroll
    for (int t = 0; t < 9; ++t)
        #pragma unroll
        for (int r = 0; r < 4; ++r) {
            const float p = __expf(sacc[t][r] - mrow[r]);
            sacc[t][r] = p;
            lrow[r] += p;
        }
    #pragma unroll
    for (int r = 0; r < 4; ++r) {
        #pragma unroll
        for (int off = 1; off < 16; off <<= 1)
            lrow[r] += __shfl_xor(lrow[r], off);
    }
    float invl[4];
    #pragma unroll
    for (int r = 0; r < 4; ++r) invl[r] = 1.f / lrow[r];

    // ---- P (bf16) -> per-wave LDS (same-wave write->read, no barrier) ----
    #pragma unroll
    for (int t = 0; t < 9; ++t)
        #pragma unroll
        for (int r = 0; r < 4; ++r)
            Pw[(g * 4 + r) * 168 + t * 16 + l15] = f2bf(sacc[t][r]);

    // ---- O = P V : A = P from LDS, B = V^T rows from swizzled Vs ----
    f32x4 oacc[4];
    #pragma unroll
    for (int nt = 0; nt < 4; ++nt)
        #pragma unroll
        for (int r = 0; r < 4; ++r) oacc[nt][r] = 0.f;

    const int kc0 = koff >> 3;                     // 0,2,4,6
    #pragma unroll
    for (int kt = 0; kt < 5; ++kt) {
        const s16x8 ap = *(const s16x8*)&Pw[l15 * 168 + kt * 32 + g * 8];
        s16x8 bvv[4];
        #pragma unroll
        for (int nt = 0; nt < 4; ++nt) {
            const int d = nt * 16 + l15;
            const int c = kc0 + kt * 4 + g;        // global chunk 0..25
            const int sl = (c < 24) ? (c ^ (d & 7)) : c;
            bvv[nt] = *(const s16x8*)&Vs[d * 208 + sl * 8];
        }
        __builtin_amdgcn_s_setprio(1);
        #pragma unroll
        for (int nt = 0; nt < 4; ++nt)
            oacc[nt] = __builtin_amdgcn_mfma_f32_16x16x32_bf16(ap, bvv[nt], oacc[nt], 0, 0, 0);
        __builtin_amdgcn_s_setprio(0);
    }

    #pragma unroll
    for (int nt = 0; nt < 4; ++nt)
        #pragma unroll
        for (int r = 0; r < 4; ++r) {
            const float val = oacc[nt][r] * invl[r];
            ob[rowbase + (size_t)(i0 + g * 4 + r) * D_ + nt * 16 + l15] = f2bf(val);
        }
}

__global__ __launch_bounds__(256) void swa_mfma4(const unsigned short* qb,
                                                 const unsigned short* __restrict__ kb,
                                                 const unsigned short* __restrict__ vt,
                                                 unsigned short* ob) {
    __shared__ __align__(16) unsigned short Ks[192 * 64];
    __shared__ __align__(16) unsigned short Vs[64 * 208];
    swa_tile(Ks, Vs, qb, kb, vt, ob, blockIdx.x);
}

// ---------------------------------------------------------------------------
// R9: persistent fused kernel — conv | QKV | swa | out-proj in ONE dispatch,
// 768 blocks (LDS union 51200 B -> exactly 3 blocks/CU; launch_bounds(256,3)
// caps VGPR <=170), software grid barriers between phases. Removes 3 kernel
// boundaries and keeps q/k/vt warm in cache across the QKV->swa edge.
// Host gates on hipOccupancyMaxActiveBlocksPerMultiprocessor >= 3 (else the
// proven 4-kernel path runs) so the barrier can never deadlock.
// Phase maps: QKV 768 tiles 1:1; swa 1024 tiles = all blocks do t=bid, blocks
// <256 also do 768+bid (same XCD as first tile); out-proj blocks <512.
// ---------------------------------------------------------------------------
__global__ __launch_bounds__(256, 3) void fused_all(const float* __restrict__ x,
                                                    const float* __restrict__ Wq,
                                                    const float* __restrict__ Wk,
                                                    const float* __restrict__ Wv,
                                                    const float* __restrict__ Wo,
                                                    unsigned short* wsb,
                                                    float* out, int* bar) {
    __shared__ __align__(16) unsigned short lds[25600];   // 51200 B union
    const size_t MD = (size_t)M_ * D_;
    const size_t WN = (size_t)D_ * D_;
    unsigned short* xb  = wsb;
    unsigned short* Wqb = xb + MD;
    unsigned short* Wob = Wqb + 3 * WN;
    unsigned short* qb  = Wob + WN;
    unsigned short* vt = (unsigned short*)out;
    unsigned short* kb = vt + MD;

    // phase 0: bf16 conversion
    conv_work(x, Wq, Wk, Wv, Wo, wsb, 768);
    gridbar(&bar[0], 768);

    // phase 1: merged QKV projection (768 tiles, 24 x 32 logical grid)
    gemm_tile<128, 128, 2, unsigned short>(lds, lds + 2 * 128 * 32,
                                           xb, Wqb, qb, kb, vt, D_,
                                           blockIdx.x, 24, 768);
    gridbar(&bar[16], 768);

    // phase 2: sliding-window attention (1024 tiles over 768 blocks)
    swa_tile(lds, lds + 192 * 64, qb, kb, vt, qb, blockIdx.x);
    if (blockIdx.x < 256)
        swa_tile(lds, lds + 192 * 64, qb, kb, vt, qb, 768 + blockIdx.x);
    gridbar(&bar[32], 768);

    // phase 3: output projection (512 tiles, 8 x 64 logical grid)
    if (blockIdx.x < 512)
        gemm_tile<64, 128, 4, float>(lds, lds + 4 * 64 * 32,
                                     qb, Wob, out, out, nullptr, D_,
                                     blockIdx.x, 8, 512);
}

extern "C" void kernel_launch(void* const* d_in, const int* in_sizes, int n_in,
                              void* d_out, int out_size, void* d_ws, size_t ws_size,
                              hipStream_t stream) {
    const float* x  = (const float*)d_in[0];
    const float* Wq = (const float*)d_in[1];
    const float* Wk = (const float*)d_in[2];
    const float* Wv = (const float*)d_in[3];
    const float* Wo = (const float*)d_in[4];

    const size_t MD = (size_t)M_ * D_;      // 4,194,304
    const size_t WN = (size_t)D_ * D_;      // 1,048,576

    // ws (bf16): xb | Wqb|Wkb|Wvb | Wob | qb  = 24 MB (+ barrier counters)
    unsigned short* wsb = (unsigned short*)d_ws;
    unsigned short* xb  = wsb;
    unsigned short* Wqb = xb + MD;          // Wq|Wk|Wv adjacent = merged B matrix
    unsigned short* Wob = Wqb + 3 * WN;
    unsigned short* qb  = Wob + WN;
    // d_out doubles as vt | kb until the final GEMM overwrites it.
    // vt FIRST: swa's V-window tail over-reads land in kb, never past d_out.
    unsigned short* vt = (unsigned short*)d_out;
    unsigned short* kb = vt + MD;

    const size_t bar_off = (MD + 4 * WN + MD) * sizeof(unsigned short);  // 24 MB
    static int cap = -1;
    if (cap < 0) {
        if (hipOccupancyMaxActiveBlocksPerMultiprocessor(&cap, fused_all, 256, 0)
            != hipSuccess) cap = 0;
    }

    if (cap >= 3 && ws_size >= bar_off + 256) {
        int* bar = (int*)((char*)d_ws + bar_off);
        hipMemsetAsync(bar, 0, 256, stream);
        fused_all<<<768, 256, 0, stream>>>(x, Wq, Wk, Wv, Wo, wsb,
                                           (float*)d_out, bar);
        return;
    }

    // Fallback: proven R8 4-kernel pipeline.
    conv_bf16<<<2048, 256, 0, stream>>>(x, Wq, Wk, Wv, Wo, wsb);
    gemm_m97<128, 128, 2, unsigned short><<<dim3(24, M_ / 128), 256, 0, stream>>>(
        xb, Wqb, qb, kb, vt, D_);
    swa_mfma4<<<(B_ * H_ * T_) / 64, 256, 0, stream>>>(qb, kb, vt, qb);
    gemm_m97<64, 128, 4, float><<<dim3(8, M_ / 64), 256, 0, stream>>>(
        qb, Wob, (float*)d_out, (float*)d_out, nullptr, D_);
}